// Round 7
// baseline (166.010 us; speedup 1.0000x reference)
//
#include <hip/hip_runtime.h>

// Problem constants (B=2, C=64, H=W=192, EXP=4, DG=4, K=3)
#define BN   2
#define CN   64
#define HN   192
#define WN   192
#define HWN  36864          // 192*192
#define OCN  256            // EXP*C
#define JCN  72             // DG*2*9
#define SN   32             // pixel strip for deform

// k_deform tile geometry
#define DROWS 8             // output rows per block
#define XH    17            // staged x rows
#define XW    43            // staged x cols
#define XRT   4             // row halo top
#define XCL   4             // col halo left
#define CI    12            // channel-interleave stride (8 ch + 4 pad, 48B: 16B-aligned)

#define PGRPS 2304          // HWN/16 pixel-groups per image

typedef __attribute__((ext_vector_type(8))) short bf16x8;
typedef __attribute__((ext_vector_type(8))) unsigned short u16x8;
typedef __attribute__((ext_vector_type(4))) float f32x4;

__device__ __forceinline__ unsigned short f2bf(float f) {
    union { float f; unsigned u; } v; v.f = f;
    unsigned r = v.u + 0x7fffu + ((v.u >> 16) & 1u);
    return (unsigned short)(r >> 16);
}

// ---------------------------------------------------------------------------
// Prep:
//  job 1: w2mf = w2 (72x256) bf16, MFMA A-frag order (tm=0..4, s=0..7)
//  job 2: w_outmf = w_out (64x64) bf16, MFMA A-frag order (tm=0..3, s=0..1)
//  job 3: w1p[o*8+kk] = w1[o*9+k(kk)], k skips center.
// ---------------------------------------------------------------------------
__global__ __launch_bounds__(256) void k_prep(const float* __restrict__ w2,
                                              const float* __restrict__ w_out,
                                              const float* __restrict__ w1,
                                              unsigned short* __restrict__ w2mf,
                                              unsigned short* __restrict__ w_outmf,
                                              float* __restrict__ w1p) {
    int idx = blockIdx.x * 256 + threadIdx.x;
    if (idx < 20480) {
        int j  = idx & 7;
        int l  = (idx >> 3) & 63;
        int ts = idx >> 9;             // tm*8+s, 0..39
        int tm = ts >> 3, s = ts & 7;
        int jrow = tm * 16 + (l & 15);
        int k    = s * 32 + (l >> 4) * 8 + j;
        float v = (jrow < JCN) ? w2[jrow * OCN + k] : 0.f;
        w2mf[idx] = f2bf(v);
    } else if (idx < 24576) {
        int r  = idx - 20480;          // 0..4095
        int j  = r & 7;
        int l  = (r >> 3) & 63;
        int ts = r >> 9;               // tm*2+s, 0..7
        int tm = ts >> 1, s = ts & 1;
        int m  = tm * 16 + (l & 15);
        int k  = s * 32 + (l >> 4) * 8 + j;
        w_outmf[r] = f2bf(w_out[m * CN + k]);
    } else if (idx < 26624) {
        int r = idx - 24576;           // 0..2047
        int o = r >> 3, kk = r & 7;
        int k = kk < 4 ? kk : kk + 1;
        w1p[r] = w1[o * 9 + k];
    }
}

// ---------------------------------------------------------------------------
// K1: offsets t + fused x1 copy.  Round-7: 2-load stencil window.
// History: r2 direct / r4 lean / r5 split-K all ~50 us with the SAME total
// load-instruction count -> bound by vector-memory REQUEST throughput.
// Fix: exploit column overlap — load only left (xcol-1) and right (xcol+1)
// taps; derive the center via cross-lane shuffle:
//   ctr = (n==15) ? shfl_up(vR,1) : shfl_down(vL,1)
// (lane n's center == lane n+1's left tap; q-group boundary lane 15 takes
// lane 14's right tap).  Load instrs per chunk: 18 -> 12 (-33% of the
// bottleneck stream); derived taps go to the idle DS/VALU pipes.
// Split-K (r5) + XCD band swizzle (r2) kept.
// ---------------------------------------------------------------------------
__global__ __launch_bounds__(512, 4) void k_offsets(const float* __restrict__ x,
                                                    const float* __restrict__ w1p,
                                                    const unsigned short* __restrict__ w2mf,
                                                    const float* __restrict__ b2,
                                                    float* __restrict__ t_out,
                                                    float* __restrict__ x_copy) {
    __shared__ float red[4 * 64 * 21];   // 21504 B; [wv][lane][20 padded to 21]

    // swizzle: orig flat id f, XCD = f%8 (round-robin); give XCD k slots
    // [144k, 144k+144) -> contiguous y-band of 48 rows per XCD.
    const int f  = blockIdx.x + 3 * blockIdx.y + 576 * blockIdx.z;
    const int nn = (f & 7) * 144 + (f >> 3);
    const int bx = nn % 3;
    const int by = (nn / 3) % 192;
    const int bz = nn / 576;

    const int tid  = threadIdx.x;
    const int wave = tid >> 6;
    const int sgrp = wave >> 2;          // K-half: 0 -> s=0..3, 1 -> s=4..7
    const int wv   = wave & 3;           // 16-pixel strip
    const int lane = tid & 63;
    const int q    = lane >> 4;
    const int n    = lane & 15;
    const int x0   = bx * 64;
    const int y    = by;
    const int b    = bz;
    const int xcol = x0 + wv * 16 + n;
    const float* xb = x + (size_t)b * CN * HWN;

    // loads: only left/right columns (center derived by shuffle)
    auto load_chunk = [&](int s, float (*lL)[3], float (*lR)[3]) {
        #pragma unroll
        for (int cc = 0; cc < 2; ++cc) {
            int c = 8 * s + 2 * q + cc;
            const float* xp = xb + (size_t)c * HWN;
            #pragma unroll
            for (int ky = 0; ky < 3; ++ky) {
                int yy = y - 1 + ky;
                int xl = xcol - 1, xr = xcol + 1;
                float vl = 0.f, vr = 0.f;
                if ((unsigned)yy < (unsigned)HN && (unsigned)xl < (unsigned)WN)
                    vl = xp[yy * WN + xl];
                if ((unsigned)yy < (unsigned)HN && (unsigned)xr < (unsigned)WN)
                    vr = xp[yy * WN + xr];
                lL[cc][ky] = vl;
                lR[cc][ky] = vr;
            }
        }
    };

    f32x4 acc[5];
    #pragma unroll
    for (int t = 0; t < 5; ++t) acc[t] = (f32x4){0.f, 0.f, 0.f, 0.f};

    const bf16x8* ap = (const bf16x8*)w2mf + lane;

    // run this wave-group's K-half with compile-time s
    #pragma unroll
    for (int sgi = 0; sgi < 2; ++sgi) {
        if (sgrp == sgi) {
            float bufL[2][2][3], bufR[2][2][3];
            load_chunk(sgi * 4, bufL[0], bufR[0]);
            #pragma unroll
            for (int ss = 0; ss < 4; ++ss) {
                const int s = sgi * 4 + ss;
                if (ss < 3) load_chunk(s + 1, bufL[(ss + 1) & 1], bufR[(ss + 1) & 1]);
                float (*lL)[3] = bufL[ss & 1];
                float (*lR)[3] = bufR[ss & 1];

                float dd[2][8];
                #pragma unroll
                for (int cc = 0; cc < 2; ++cc) {
                    // derive the 3 center taps via cross-lane shuffle
                    float ctr3[3];
                    #pragma unroll
                    for (int ky = 0; ky < 3; ++ky) {
                        float cA = __shfl_down(lL[cc][ky], 1);
                        float cB = __shfl_up(lR[cc][ky], 1);
                        ctr3[ky] = (n == 15) ? cB : cA;
                    }
                    const float ctr = ctr3[1];
                    int c = 8 * s + 2 * q + cc;
                    x_copy[((size_t)b * CN + c) * HWN + y * WN + xcol] = ctr;
                    // taps: kx=0 -> lL[ky], kx=1 -> ctr3[ky], kx=2 -> lR[ky]
                    dd[cc][0] = lL[cc][0]  - ctr;   // k=0 (0,0)
                    dd[cc][1] = ctr3[0]    - ctr;   // k=1 (0,1)
                    dd[cc][2] = lR[cc][0]  - ctr;   // k=2 (0,2)
                    dd[cc][3] = lL[cc][1]  - ctr;   // k=3 (1,0)
                    dd[cc][4] = lR[cc][1]  - ctr;   // k=5 (1,2)
                    dd[cc][5] = lL[cc][2]  - ctr;   // k=6 (2,0)
                    dd[cc][6] = ctr3[2]    - ctr;   // k=7 (2,1)
                    dd[cc][7] = lR[cc][2]  - ctr;   // k=8 (2,2)
                }

                bf16x8 bfr;
                const float4* wp = (const float4*)(w1p + (size_t)(s * 32 + q * 8) * 8);
                #pragma unroll
                for (int j = 0; j < 8; ++j) {
                    float4 wa = wp[2 * j];
                    float4 wb = wp[2 * j + 1];
                    const float* d = dd[j >> 2];
                    float a = wa.x * d[0] + wa.y * d[1] + wa.z * d[2] + wa.w * d[3]
                            + wb.x * d[4] + wb.y * d[5] + wb.z * d[6] + wb.w * d[7];
                    bfr[j] = (short)f2bf(a);
                }

                #pragma unroll
                for (int tm = 0; tm < 5; ++tm) {
                    bf16x8 af = ap[(tm * 8 + s) * 64];
                    acc[tm] = __builtin_amdgcn_mfma_f32_16x16x32_bf16(af, bfr, acc[tm], 0, 0, 0);
                }
            }
        }
    }

    // combine the two K-halves via LDS (stride 21: conflict-free)
    float* rp = &red[(wv * 64 + lane) * 21];
    if (sgrp == 1) {
        #pragma unroll
        for (int tm = 0; tm < 5; ++tm)
            #pragma unroll
            for (int r = 0; r < 4; ++r)
                rp[tm * 4 + r] = acc[tm][r];
    }
    __syncthreads();
    if (sgrp == 0) {
        // Epilogue (D layout: col=lane&15, row=q*4+reg)
        float* tb = t_out + (size_t)b * JCN * HWN + y * WN + x0 + wv * 16 + n;
        #pragma unroll
        for (int tm = 0; tm < 5; ++tm) {
            #pragma unroll
            for (int r = 0; r < 4; ++r) {
                int j = tm * 16 + q * 4 + r;
                if (j < JCN)
                    tb[(size_t)j * HWN] = acc[tm][r] + rp[tm * 4 + r] + b2[j];
            }
        }
    }
}

// ---------------------------------------------------------------------------
// K2: depthwise deformable conv.  Channel-interleaved LDS window (r6:
// conflicts 8.3M -> low, 47.5 -> <47).  y written bf16 in MFMA B-frag order.
// XCD swizzle pairs both chunks of a deform group on the same XCD.
// ---------------------------------------------------------------------------
__device__ __forceinline__ float dsample(const float* __restrict__ p, int yi, int xi) {
    if ((unsigned)yi < (unsigned)HN && (unsigned)xi < (unsigned)WN)
        return p[yi * WN + xi];
    return 0.f;
}

__global__ __launch_bounds__(256, 4) void k_deform(const float* __restrict__ x,
                                                   const float* __restrict__ t_in,
                                                   const float* __restrict__ wdef,
                                                   unsigned short* __restrict__ y_out) {
    __shared__ float xs[XH * XW * CI];                // 35088 B
    __shared__ float wks[9 * 8];                      // [k][cc]
    __shared__ float wsums[8];

    // swizzle: 2304 blocks = 8 XCD * 288 slots; slot = (tile<<1)|cm;
    // XCD k runs zz = {2k, 2k+1} = both chunks of deform-group g=k%4, b=k/4.
    const int f    = blockIdx.x + 6 * blockIdx.y + 144 * blockIdx.z;  // 0..2303
    const int slot = f >> 3;
    const int xcd  = f & 7;
    const int tile = slot >> 1;
    const int cm   = slot & 1;
    const int zz   = 2 * xcd + cm;            // 0..15
    const int bx   = tile % 6;
    const int byy  = tile / 6;

    const int x0   = bx * SN;
    const int yr0  = byy * DROWS;
    const int b    = zz >> 3;
    const int chunk = zz & 7;                 // 8-channel chunk
    const int g    = chunk >> 1;              // deform group
    const int tid  = threadIdx.x;
    const int r    = tid >> 5;                // output row within tile
    const int px   = tid & 31;
    const int row_lo = yr0 - XRT;
    const int col_lo = x0 - XCL;
    const float* xb = x + (size_t)b * CN * HWN;

    // prefetch this thread's 18 offsets into registers (coalesced)
    float dyr[9], dxr[9];
    {
        const float* tbp = t_in + ((size_t)b * JCN + g * 18) * HWN
                         + (yr0 + r) * WN + x0 + px;
        #pragma unroll
        for (int k = 0; k < 9; ++k) {
            dyr[k] = tbp[(size_t)(2 * k) * HWN];
            dxr[k] = tbp[(size_t)(2 * k + 1) * HWN];
        }
    }

    // stage x window (zero-filled outside image), channel-interleaved
    for (int idx = tid; idx < 8 * XH * XW; idx += 256) {
        int cc  = idx / (XH * XW);
        int rem = idx - cc * (XH * XW);
        int rr  = rem / XW;
        int col = rem - rr * XW;
        int yy  = row_lo + rr;
        int xx  = col_lo + col;
        float v = 0.f;
        if ((unsigned)yy < (unsigned)HN && (unsigned)xx < (unsigned)WN)
            v = xb[(size_t)(chunk * 8 + cc) * HWN + yy * WN + xx];
        xs[(rr * XW + col) * CI + cc] = v;
    }
    // stage weights
    if (tid < 72) {
        int k = tid >> 3, cc = tid & 7;
        wks[tid] = wdef[(chunk * 8 + cc) * 9 + k];
    } else if (tid < 80) {
        int cc = tid - 72;
        float s = 0.f;
        #pragma unroll
        for (int k = 0; k < 9; ++k) s += wdef[(chunk * 8 + cc) * 9 + k];
        wsums[cc] = s;
    }
    __syncthreads();

    float acc[8];
    {
        const float* ctr = xs + ((XRT + r) * XW + XCL + px) * CI;
        f32x4 c0 = *(const f32x4*)ctr;
        f32x4 c1 = *(const f32x4*)(ctr + 4);
        f32x4 w0 = *(const f32x4*)&wsums[0];
        f32x4 w1 = *(const f32x4*)&wsums[4];
        #pragma unroll
        for (int i = 0; i < 4; ++i) {
            acc[i]     = -c0[i] * w0[i];
            acc[4 + i] = -c1[i] * w1[i];
        }
    }

    const float ry_basef = (float)(yr0 + r - 1);
    const float rx_basef = (float)(x0 + px - 1);

    #pragma unroll
    for (int k = 0; k < 9; ++k) {
        const int ky = k / 3, kx = k - 3 * ky;
        float py  = ry_basef + (float)ky + dyr[k];
        float pxf = rx_basef + (float)kx + dxr[k];
        float y0f = floorf(py), x0f = floorf(pxf);
        float wy = py - y0f, wx = pxf - x0f;
        int yi = (int)y0f, xi = (int)x0f;
        int ry = yi - row_lo, rx = xi - col_lo;
        float omwy = 1.f - wy, omwx = 1.f - wx;
        float w00 = omwy * omwx;
        float w01 = omwy * wx;
        float w10 = wy * omwx;
        float w11 = wy * wx;
        float4 wka = *(const float4*)&wks[k * 8];
        float4 wkb = *(const float4*)&wks[k * 8 + 4];
        if ((unsigned)ry < (XH - 1) && (unsigned)rx < (XW - 1)) {
            const float* p00 = xs + (ry * XW + rx) * CI;
            const float* p10 = p00 + XW * CI;
            f32x4 a0 = *(const f32x4*)p00;            // (ry, rx)   ch0-3
            f32x4 a1 = *(const f32x4*)(p00 + 4);      //            ch4-7
            f32x4 b0 = *(const f32x4*)(p00 + CI);     // (ry, rx+1) ch0-3
            f32x4 b1 = *(const f32x4*)(p00 + CI + 4);
            f32x4 c0 = *(const f32x4*)p10;            // (ry+1, rx) ch0-3
            f32x4 c1 = *(const f32x4*)(p10 + 4);
            f32x4 d0 = *(const f32x4*)(p10 + CI);     // (ry+1,rx+1)ch0-3
            f32x4 d1 = *(const f32x4*)(p10 + CI + 4);
            #pragma unroll
            for (int i = 0; i < 4; ++i) {
                float bil0 = a0[i] * w00 + b0[i] * w01 + c0[i] * w10 + d0[i] * w11;
                float bil1 = a1[i] * w00 + b1[i] * w01 + c1[i] * w10 + d1[i] * w11;
                acc[i]     += (&wka.x)[i] * bil0;
                acc[4 + i] += (&wkb.x)[i] * bil1;
            }
        } else {
            float wkv[8] = {wka.x, wka.y, wka.z, wka.w, wkb.x, wkb.y, wkb.z, wkb.w};
            #pragma unroll
            for (int c = 0; c < 8; ++c) {
                const float* xp = xb + (size_t)(chunk * 8 + c) * HWN;
                float v00 = dsample(xp, yi,     xi);
                float v01 = dsample(xp, yi,     xi + 1);
                float v10 = dsample(xp, yi + 1, xi);
                float v11 = dsample(xp, yi + 1, xi + 1);
                float bil = v00 * w00 + v01 * w01 + v10 * w10 + v11 * w11;
                acc[c] += wkv[c] * bil;
            }
        }
    }

    // bf16 B-frag store: y_bf[b][P][s][q][n][j], j contiguous (16B / thread)
    u16x8 pk;
    #pragma unroll
    for (int c = 0; c < 8; ++c) pk[c] = f2bf(acc[c]);
    const int P = (yr0 + r) * (WN / 16) + ((x0 + px) >> 4);
    unsigned short* yo = y_out
        + ((((size_t)b * PGRPS + P) * 2 + (chunk >> 2)) * 4 + (chunk & 3)) * 128
        + (px & 15) * 8;
    *(u16x8*)yo = pk;
}

// ---------------------------------------------------------------------------
// K3: m = w_out . y via MFMA.  Round-7: LDS transpose epilogue — the 16
// scalar plane-strided stores become 4 coalesced float4 stores per thread
// (store instrs 4x fewer, 1KB per wave-instr).
// ---------------------------------------------------------------------------
__global__ __launch_bounds__(256, 8) void k_final(const unsigned short* __restrict__ y_bf,
                                                  const unsigned short* __restrict__ womf,
                                                  float* __restrict__ m_out) {
    __shared__ float ms[64 * 68];        // 17408 B, stride 68 (16B-aligned rows)

    const int tid  = threadIdx.x;
    const int wv   = tid >> 6;
    const int lane = tid & 63;
    const int q    = lane >> 4;
    const int n    = lane & 15;
    const int yr   = blockIdx.y;
    const int b    = blockIdx.z;
    const int P    = yr * (WN / 16) + blockIdx.x * 4 + wv;

    const unsigned short* yp = y_bf + ((size_t)b * PGRPS + P) * 1024;
    bf16x8 bfr0 = *(const bf16x8*)(yp + (0 * 64 + q * 16 + n) * 8);
    bf16x8 bfr1 = *(const bf16x8*)(yp + (1 * 64 + q * 16 + n) * 8);

    const bf16x8* ap = (const bf16x8*)womf + lane;
    f32x4 acc[4];
    #pragma unroll
    for (int tm = 0; tm < 4; ++tm) acc[tm] = (f32x4){0.f, 0.f, 0.f, 0.f};
    #pragma unroll
    for (int tm = 0; tm < 4; ++tm) {
        acc[tm] = __builtin_amdgcn_mfma_f32_16x16x32_bf16(ap[(tm * 2 + 0) * 64], bfr0, acc[tm], 0, 0, 0);
        acc[tm] = __builtin_amdgcn_mfma_f32_16x16x32_bf16(ap[(tm * 2 + 1) * 64], bfr1, acc[tm], 0, 0, 0);
    }

    // D layout: col=lane&15, row=q*4+reg ; o = tm*16 + q*4 + r, col = wv*16+n
    #pragma unroll
    for (int tm = 0; tm < 4; ++tm)
        #pragma unroll
        for (int r = 0; r < 4; ++r)
            ms[(tm * 16 + q * 4 + r) * 68 + wv * 16 + n] = acc[tm][r];
    __syncthreads();

    // coalesced write-out: thread -> (o = tid>>2, 16-col segment = tid&3)
    const int o  = tid >> 2;
    const int sg = tid & 3;
    float* mb = m_out + (size_t)b * CN * HWN + (size_t)o * HWN + yr * WN
              + blockIdx.x * 64 + sg * 16;
    const float* mr = &ms[o * 68 + sg * 16];
    #pragma unroll
    for (int i = 0; i < 4; ++i) {
        float4 v = *(const float4*)(mr + 4 * i);
        *(float4*)(mb + 4 * i) = v;
    }
}

// ---------------------------------------------------------------------------
extern "C" void kernel_launch(void* const* d_in, const int* in_sizes, int n_in,
                              void* d_out, int out_size, void* d_ws, size_t ws_size,
                              hipStream_t stream) {
    const float* x1    = (const float*)d_in[0];   // 2*64*192*192
    const float* w_off1 = (const float*)d_in[1];  // 256*9
    const float* w_off2 = (const float*)d_in[2];  // 72*256
    const float* b_off2 = (const float*)d_in[3];  // 72
    const float* w_def = (const float*)d_in[4];   // 64*9
    const float* w_out = (const float*)d_in[5];   // 64*64

    float* out = (float*)d_out;
    const size_t n_x = (size_t)BN * CN * HWN;     // 4718592
    float* out_x1 = out;                          // output 0: x1 copy (fused into k_offsets)
    float* out_m  = out + n_x;                    // output 1: m

    // Workspace layout (bytes)
    char* ws0 = (char*)d_ws;
    unsigned short* w2mf   = (unsigned short*)ws0;            // 20480 bf16 = 40960 B
    unsigned short* w_outmf = (unsigned short*)(ws0 + 40960); // 4096 bf16 = 8192 B
    float* w1p    = (float*)(ws0 + 49152);                    // 2048 f = 8192 B
    float* t_ws   = (float*)(ws0 + 57344);                    // 2*72*36864 f = 21233664 B
    unsigned short* y_bf = (unsigned short*)(ws0 + 57344 + 21233664); // 2*2304*1024 u16 = 9.44 MB

    k_prep<<<dim3(104), dim3(256), 0, stream>>>(w_off2, w_out, w_off1, w2mf, w_outmf, w1p);
    k_offsets<<<dim3(WN / 64, HN, BN), dim3(512), 0, stream>>>(x1, w1p, w2mf, b_off2,
                                                               t_ws, out_x1);
    k_deform<<<dim3(WN / SN, HN / DROWS, BN * 8), dim3(256), 0, stream>>>(x1, t_ws, w_def, y_bf);
    k_final<<<dim3(WN / 64, HN, BN), dim3(256), 0, stream>>>(y_bf, w_outmf, out_m);
}

// Round 8
// 162.195 us; speedup vs baseline: 1.0235x; 1.0235x over previous
//
#include <hip/hip_runtime.h>

// Problem constants (B=2, C=64, H=W=192, EXP=4, DG=4, K=3)
#define BN   2
#define CN   64
#define HN   192
#define WN   192
#define HWN  36864          // 192*192
#define OCN  256            // EXP*C
#define JCN  72             // DG*2*9
#define SN   32             // pixel strip for deform

// k_deform tile geometry
#define DROWS 8             // output rows per block
#define XH    17            // staged x rows
#define XW    43            // staged x cols
#define XRT   4             // row halo top
#define XCL   4             // col halo left
#define CI    12            // channel-interleave stride (8 ch + 4 pad, 48B: 16B-aligned)

#define PGRPS 2304          // HWN/16 pixel-groups per image

typedef __attribute__((ext_vector_type(8))) short bf16x8;
typedef __attribute__((ext_vector_type(8))) unsigned short u16x8;
typedef __attribute__((ext_vector_type(4))) float f32x4;

__device__ __forceinline__ unsigned short f2bf(float f) {
    union { float f; unsigned u; } v; v.f = f;
    unsigned r = v.u + 0x7fffu + ((v.u >> 16) & 1u);
    return (unsigned short)(r >> 16);
}

// ---------------------------------------------------------------------------
// Prep:
//  job 1: w2mf = w2 (72x256) bf16, MFMA A-frag order (tm=0..4, s=0..7)
//  job 2: w_outmf = w_out (64x64) bf16, MFMA A-frag order (tm=0..3, s=0..1)
//  job 3: w1p[o*8+kk] = w1[o*9+k(kk)], k skips center.
// ---------------------------------------------------------------------------
__global__ __launch_bounds__(256) void k_prep(const float* __restrict__ w2,
                                              const float* __restrict__ w_out,
                                              const float* __restrict__ w1,
                                              unsigned short* __restrict__ w2mf,
                                              unsigned short* __restrict__ w_outmf,
                                              float* __restrict__ w1p) {
    int idx = blockIdx.x * 256 + threadIdx.x;
    if (idx < 20480) {
        int j  = idx & 7;
        int l  = (idx >> 3) & 63;
        int ts = idx >> 9;             // tm*8+s, 0..39
        int tm = ts >> 3, s = ts & 7;
        int jrow = tm * 16 + (l & 15);
        int k    = s * 32 + (l >> 4) * 8 + j;
        float v = (jrow < JCN) ? w2[jrow * OCN + k] : 0.f;
        w2mf[idx] = f2bf(v);
    } else if (idx < 24576) {
        int r  = idx - 20480;          // 0..4095
        int j  = r & 7;
        int l  = (r >> 3) & 63;
        int ts = r >> 9;               // tm*2+s, 0..7
        int tm = ts >> 1, s = ts & 1;
        int m  = tm * 16 + (l & 15);
        int k  = s * 32 + (l >> 4) * 8 + j;
        w_outmf[r] = f2bf(w_out[m * CN + k]);
    } else if (idx < 26624) {
        int r = idx - 24576;           // 0..2047
        int o = r >> 3, kk = r & 7;
        int k = kk < 4 ? kk : kk + 1;
        w1p[r] = w1[o * 9 + k];
    }
}

// ---------------------------------------------------------------------------
// K1: offsets t + fused x1 copy.  Round-8: r2 direct body (known-good
// scheduling) + prefetch distance 2.
// History: r2 direct=51, r3 LDS-stage=77, r4 lean-instr=70, r5 split-K=51,
// r7 shuffle-stencil=52.  Counters across all: VALU ~20%, HBM ~14%, MFMA 2%,
// occupancy ~9 waves/CU -> memory-LATENCY-bound, thin TLP.  Only never-tried
// lever: deeper per-wave MLP.  Distance 2 (lbuf[3], 36 loads in flight)
// needs >64 VGPR -> launch_bounds(256,2) lifts the cap (occupancy is 9
// waves/CU anyway; VGPRs are abundant).
// XCD band swizzle kept (FETCH 46.9 -> 12.3 MB).
// ---------------------------------------------------------------------------
__global__ __launch_bounds__(256, 2) void k_offsets(const float* __restrict__ x,
                                                    const float* __restrict__ w1p,
                                                    const unsigned short* __restrict__ w2mf,
                                                    const float* __restrict__ b2,
                                                    float* __restrict__ t_out,
                                                    float* __restrict__ x_copy) {
    // swizzle: orig flat id f, XCD = f%8 (round-robin); give XCD k slots
    // [144k, 144k+144) -> contiguous y-band of 48 rows per XCD.
    const int f  = blockIdx.x + 3 * blockIdx.y + 576 * blockIdx.z;
    const int nn = (f & 7) * 144 + (f >> 3);
    const int bx = nn % 3;
    const int by = (nn / 3) % 192;
    const int bz = nn / 576;

    const int tid  = threadIdx.x;
    const int wv   = tid >> 6;
    const int lane = tid & 63;
    const int q    = lane >> 4;
    const int n    = lane & 15;
    const int n0   = bx * 64 + wv * 16;
    const int y    = by;
    const int b    = bz;
    const int xcol = n0 + n;
    const float* xb = x + (size_t)b * CN * HWN;

    auto load_chunk = [&](int s, float (*ld)[9]) {
        #pragma unroll
        for (int cc = 0; cc < 2; ++cc) {
            int c = 8 * s + 2 * q + cc;
            const float* xp = xb + (size_t)c * HWN;
            #pragma unroll
            for (int k = 0; k < 9; ++k) {
                int ky = k / 3, kx = k - 3 * ky;
                int yy = y - 1 + ky, xx = xcol - 1 + kx;
                float v = 0.f;
                if ((unsigned)yy < (unsigned)HN && (unsigned)xx < (unsigned)WN)
                    v = xp[yy * WN + xx];
                ld[cc][k] = v;
            }
        }
    };

    f32x4 acc[5];
    #pragma unroll
    for (int t = 0; t < 5; ++t) acc[t] = (f32x4){0.f, 0.f, 0.f, 0.f};

    const bf16x8* ap = (const bf16x8*)w2mf + lane;

    float lbuf[3][2][9];
    load_chunk(0, lbuf[0]);
    load_chunk(1, lbuf[1]);
    #pragma unroll
    for (int s = 0; s < 8; ++s) {
        if (s < 6) load_chunk(s + 2, lbuf[(s + 2) % 3]);
        float (*ld)[9] = lbuf[s % 3];

        float dd[2][8];
        #pragma unroll
        for (int cc = 0; cc < 2; ++cc) {
            int c = 8 * s + 2 * q + cc;
            float ctr = ld[cc][4];
            x_copy[((size_t)b * CN + c) * HWN + y * WN + xcol] = ctr;
            #pragma unroll
            for (int kk = 0; kk < 8; ++kk) {
                int k = kk < 4 ? kk : kk + 1;
                dd[cc][kk] = ld[cc][k] - ctr;
            }
        }

        bf16x8 bfr;
        const float4* wp = (const float4*)(w1p + (size_t)(s * 32 + q * 8) * 8);
        #pragma unroll
        for (int j = 0; j < 8; ++j) {
            float4 wa = wp[2 * j];
            float4 wb = wp[2 * j + 1];
            const float* d = dd[j >> 2];
            float a = wa.x * d[0] + wa.y * d[1] + wa.z * d[2] + wa.w * d[3]
                    + wb.x * d[4] + wb.y * d[5] + wb.z * d[6] + wb.w * d[7];
            bfr[j] = (short)f2bf(a);
        }

        #pragma unroll
        for (int tm = 0; tm < 5; ++tm) {
            bf16x8 af = ap[(tm * 8 + s) * 64];
            acc[tm] = __builtin_amdgcn_mfma_f32_16x16x32_bf16(af, bfr, acc[tm], 0, 0, 0);
        }
    }

    // Epilogue (D layout: col=lane&15, row=q*4+reg)
    float* tb = t_out + (size_t)b * JCN * HWN + y * WN + n0 + n;
    #pragma unroll
    for (int tm = 0; tm < 5; ++tm) {
        #pragma unroll
        for (int r = 0; r < 4; ++r) {
            int j = tm * 16 + q * 4 + r;
            if (j < JCN)
                tb[(size_t)j * HWN] = acc[tm][r] + b2[j];
        }
    }
}

// ---------------------------------------------------------------------------
// K2: depthwise deformable conv.  Channel-interleaved LDS window (r6 win:
// 2 x ds_read_b128 per 8-ch corner instead of 8 x ds_read_b32).  y written
// bf16 in MFMA B-frag order (one 16B store/thread).  XCD swizzle pairs both
// chunks of a deform group on the same XCD.
// ---------------------------------------------------------------------------
__device__ __forceinline__ float dsample(const float* __restrict__ p, int yi, int xi) {
    if ((unsigned)yi < (unsigned)HN && (unsigned)xi < (unsigned)WN)
        return p[yi * WN + xi];
    return 0.f;
}

__global__ __launch_bounds__(256, 4) void k_deform(const float* __restrict__ x,
                                                   const float* __restrict__ t_in,
                                                   const float* __restrict__ wdef,
                                                   unsigned short* __restrict__ y_out) {
    __shared__ float xs[XH * XW * CI];                // 35088 B
    __shared__ float wks[9 * 8];                      // [k][cc]
    __shared__ float wsums[8];

    // swizzle: 2304 blocks = 8 XCD * 288 slots; slot = (tile<<1)|cm;
    // XCD k runs zz = {2k, 2k+1} = both chunks of deform-group g=k%4, b=k/4.
    const int f    = blockIdx.x + 6 * blockIdx.y + 144 * blockIdx.z;  // 0..2303
    const int slot = f >> 3;
    const int xcd  = f & 7;
    const int tile = slot >> 1;
    const int cm   = slot & 1;
    const int zz   = 2 * xcd + cm;            // 0..15
    const int bx   = tile % 6;
    const int byy  = tile / 6;

    const int x0   = bx * SN;
    const int yr0  = byy * DROWS;
    const int b    = zz >> 3;
    const int chunk = zz & 7;                 // 8-channel chunk
    const int g    = chunk >> 1;              // deform group
    const int tid  = threadIdx.x;
    const int r    = tid >> 5;                // output row within tile
    const int px   = tid & 31;
    const int row_lo = yr0 - XRT;
    const int col_lo = x0 - XCL;
    const float* xb = x + (size_t)b * CN * HWN;

    // prefetch this thread's 18 offsets into registers (coalesced)
    float dyr[9], dxr[9];
    {
        const float* tbp = t_in + ((size_t)b * JCN + g * 18) * HWN
                         + (yr0 + r) * WN + x0 + px;
        #pragma unroll
        for (int k = 0; k < 9; ++k) {
            dyr[k] = tbp[(size_t)(2 * k) * HWN];
            dxr[k] = tbp[(size_t)(2 * k + 1) * HWN];
        }
    }

    // stage x window (zero-filled outside image), channel-interleaved
    for (int idx = tid; idx < 8 * XH * XW; idx += 256) {
        int cc  = idx / (XH * XW);
        int rem = idx - cc * (XH * XW);
        int rr  = rem / XW;
        int col = rem - rr * XW;
        int yy  = row_lo + rr;
        int xx  = col_lo + col;
        float v = 0.f;
        if ((unsigned)yy < (unsigned)HN && (unsigned)xx < (unsigned)WN)
            v = xb[(size_t)(chunk * 8 + cc) * HWN + yy * WN + xx];
        xs[(rr * XW + col) * CI + cc] = v;
    }
    // stage weights
    if (tid < 72) {
        int k = tid >> 3, cc = tid & 7;
        wks[tid] = wdef[(chunk * 8 + cc) * 9 + k];
    } else if (tid < 80) {
        int cc = tid - 72;
        float s = 0.f;
        #pragma unroll
        for (int k = 0; k < 9; ++k) s += wdef[(chunk * 8 + cc) * 9 + k];
        wsums[cc] = s;
    }
    __syncthreads();

    float acc[8];
    {
        const float* ctr = xs + ((XRT + r) * XW + XCL + px) * CI;
        f32x4 c0 = *(const f32x4*)ctr;
        f32x4 c1 = *(const f32x4*)(ctr + 4);
        f32x4 w0 = *(const f32x4*)&wsums[0];
        f32x4 w1 = *(const f32x4*)&wsums[4];
        #pragma unroll
        for (int i = 0; i < 4; ++i) {
            acc[i]     = -c0[i] * w0[i];
            acc[4 + i] = -c1[i] * w1[i];
        }
    }

    const float ry_basef = (float)(yr0 + r - 1);
    const float rx_basef = (float)(x0 + px - 1);

    #pragma unroll
    for (int k = 0; k < 9; ++k) {
        const int ky = k / 3, kx = k - 3 * ky;
        float py  = ry_basef + (float)ky + dyr[k];
        float pxf = rx_basef + (float)kx + dxr[k];
        float y0f = floorf(py), x0f = floorf(pxf);
        float wy = py - y0f, wx = pxf - x0f;
        int yi = (int)y0f, xi = (int)x0f;
        int ry = yi - row_lo, rx = xi - col_lo;
        float omwy = 1.f - wy, omwx = 1.f - wx;
        float w00 = omwy * omwx;
        float w01 = omwy * wx;
        float w10 = wy * omwx;
        float w11 = wy * wx;
        float4 wka = *(const float4*)&wks[k * 8];
        float4 wkb = *(const float4*)&wks[k * 8 + 4];
        if ((unsigned)ry < (XH - 1) && (unsigned)rx < (XW - 1)) {
            const float* p00 = xs + (ry * XW + rx) * CI;
            const float* p10 = p00 + XW * CI;
            f32x4 a0 = *(const f32x4*)p00;            // (ry, rx)   ch0-3
            f32x4 a1 = *(const f32x4*)(p00 + 4);      //            ch4-7
            f32x4 b0 = *(const f32x4*)(p00 + CI);     // (ry, rx+1) ch0-3
            f32x4 b1 = *(const f32x4*)(p00 + CI + 4);
            f32x4 c0 = *(const f32x4*)p10;            // (ry+1, rx) ch0-3
            f32x4 c1 = *(const f32x4*)(p10 + 4);
            f32x4 d0 = *(const f32x4*)(p10 + CI);     // (ry+1,rx+1)ch0-3
            f32x4 d1 = *(const f32x4*)(p10 + CI + 4);
            #pragma unroll
            for (int i = 0; i < 4; ++i) {
                float bil0 = a0[i] * w00 + b0[i] * w01 + c0[i] * w10 + d0[i] * w11;
                float bil1 = a1[i] * w00 + b1[i] * w01 + c1[i] * w10 + d1[i] * w11;
                acc[i]     += (&wka.x)[i] * bil0;
                acc[4 + i] += (&wkb.x)[i] * bil1;
            }
        } else {
            float wkv[8] = {wka.x, wka.y, wka.z, wka.w, wkb.x, wkb.y, wkb.z, wkb.w};
            #pragma unroll
            for (int c = 0; c < 8; ++c) {
                const float* xp = xb + (size_t)(chunk * 8 + c) * HWN;
                float v00 = dsample(xp, yi,     xi);
                float v01 = dsample(xp, yi,     xi + 1);
                float v10 = dsample(xp, yi + 1, xi);
                float v11 = dsample(xp, yi + 1, xi + 1);
                float bil = v00 * w00 + v01 * w01 + v10 * w10 + v11 * w11;
                acc[c] += wkv[c] * bil;
            }
        }
    }

    // bf16 B-frag store: y_bf[b][P][s][q][n][j], j contiguous (16B / thread)
    u16x8 pk;
    #pragma unroll
    for (int c = 0; c < 8; ++c) pk[c] = f2bf(acc[c]);
    const int P = (yr0 + r) * (WN / 16) + ((x0 + px) >> 4);
    unsigned short* yo = y_out
        + ((((size_t)b * PGRPS + P) * 2 + (chunk >> 2)) * 4 + (chunk & 3)) * 128
        + (px & 15) * 8;
    *(u16x8*)yo = pk;
}

// ---------------------------------------------------------------------------
// K3: m = w_out . y via MFMA.  y arrives bf16 in B-frag order: two 16B loads
// per thread replace 64 scalar plane-strided loads + 64 f2bf.  (r7's LDS
// transpose epilogue regressed the total — reverted to direct stores.)
// ---------------------------------------------------------------------------
__global__ __launch_bounds__(256, 8) void k_final(const unsigned short* __restrict__ y_bf,
                                                  const unsigned short* __restrict__ womf,
                                                  float* __restrict__ m_out) {
    const int tid  = threadIdx.x;
    const int wv   = tid >> 6;
    const int lane = tid & 63;
    const int q    = lane >> 4;
    const int n    = lane & 15;
    const int yr   = blockIdx.y;
    const int b    = blockIdx.z;
    const int P    = yr * (WN / 16) + blockIdx.x * 4 + wv;

    const unsigned short* yp = y_bf + ((size_t)b * PGRPS + P) * 1024;
    bf16x8 bfr0 = *(const bf16x8*)(yp + (0 * 64 + q * 16 + n) * 8);
    bf16x8 bfr1 = *(const bf16x8*)(yp + (1 * 64 + q * 16 + n) * 8);

    const bf16x8* ap = (const bf16x8*)womf + lane;
    f32x4 acc[4];
    #pragma unroll
    for (int tm = 0; tm < 4; ++tm) acc[tm] = (f32x4){0.f, 0.f, 0.f, 0.f};
    #pragma unroll
    for (int tm = 0; tm < 4; ++tm) {
        acc[tm] = __builtin_amdgcn_mfma_f32_16x16x32_bf16(ap[(tm * 2 + 0) * 64], bfr0, acc[tm], 0, 0, 0);
        acc[tm] = __builtin_amdgcn_mfma_f32_16x16x32_bf16(ap[(tm * 2 + 1) * 64], bfr1, acc[tm], 0, 0, 0);
    }

    // D layout: col=lane&15, row=q*4+reg ; o = tm*16 + q*4 + r
    float* mb = m_out + (size_t)b * CN * HWN + yr * WN + blockIdx.x * 64 + wv * 16 + n;
    #pragma unroll
    for (int tm = 0; tm < 4; ++tm) {
        #pragma unroll
        for (int r = 0; r < 4; ++r)
            mb[(size_t)(tm * 16 + q * 4 + r) * HWN] = acc[tm][r];
    }
}

// ---------------------------------------------------------------------------
extern "C" void kernel_launch(void* const* d_in, const int* in_sizes, int n_in,
                              void* d_out, int out_size, void* d_ws, size_t ws_size,
                              hipStream_t stream) {
    const float* x1    = (const float*)d_in[0];   // 2*64*192*192
    const float* w_off1 = (const float*)d_in[1];  // 256*9
    const float* w_off2 = (const float*)d_in[2];  // 72*256
    const float* b_off2 = (const float*)d_in[3];  // 72
    const float* w_def = (const float*)d_in[4];   // 64*9
    const float* w_out = (const float*)d_in[5];   // 64*64

    float* out = (float*)d_out;
    const size_t n_x = (size_t)BN * CN * HWN;     // 4718592
    float* out_x1 = out;                          // output 0: x1 copy (fused into k_offsets)
    float* out_m  = out + n_x;                    // output 1: m

    // Workspace layout (bytes)
    char* ws0 = (char*)d_ws;
    unsigned short* w2mf   = (unsigned short*)ws0;            // 20480 bf16 = 40960 B
    unsigned short* w_outmf = (unsigned short*)(ws0 + 40960); // 4096 bf16 = 8192 B
    float* w1p    = (float*)(ws0 + 49152);                    // 2048 f = 8192 B
    float* t_ws   = (float*)(ws0 + 57344);                    // 2*72*36864 f = 21233664 B
    unsigned short* y_bf = (unsigned short*)(ws0 + 57344 + 21233664); // 2*2304*1024 u16 = 9.44 MB

    k_prep<<<dim3(104), dim3(256), 0, stream>>>(w_off2, w_out, w_off1, w2mf, w_outmf, w1p);
    k_offsets<<<dim3(WN / 64, HN, BN), dim3(256), 0, stream>>>(x1, w1p, w2mf, b_off2,
                                                               t_ws, out_x1);
    k_deform<<<dim3(WN / SN, HN / DROWS, BN * 8), dim3(256), 0, stream>>>(x1, t_ws, w_def, y_bf);
    k_final<<<dim3(WN / 64, HN, BN), dim3(256), 0, stream>>>(y_bf, w_outmf, out_m);
}

// Round 9
// 154.071 us; speedup vs baseline: 1.0775x; 1.0527x over previous
//
#include <hip/hip_runtime.h>

// Problem constants (B=2, C=64, H=W=192, EXP=4, DG=4, K=3)
#define BN   2
#define CN   64
#define HN   192
#define WN   192
#define HWN  36864          // 192*192
#define OCN  256            // EXP*C
#define JCN  72             // DG*2*9
#define SN   32             // pixel strip for deform

// k_deform tile geometry — round 9: halo 4 -> 2 (|t| ~ N(0,0.2^2); taps
// beyond the window take the correct global-path else-branch).  LDS 35.1 ->
// 23.1 KB: 4 -> 7 blocks/CU.
#define DROWS 8             // output rows per block
#define XH    13            // staged x rows  (2 + 8 + 3)
#define XW    37            // staged x cols  (2 + 32 + 3)
#define XRT   2             // row halo top
#define XCL   2             // col halo left
#define CI    12            // channel-interleave stride (8 ch + 4 pad, 48B: 16B-aligned)

#define PGRPS 2304          // HWN/16 pixel-groups per image

typedef __attribute__((ext_vector_type(8))) short bf16x8;
typedef __attribute__((ext_vector_type(8))) unsigned short u16x8;
typedef __attribute__((ext_vector_type(4))) float f32x4;

__device__ __forceinline__ unsigned short f2bf(float f) {
    union { float f; unsigned u; } v; v.f = f;
    unsigned r = v.u + 0x7fffu + ((v.u >> 16) & 1u);
    return (unsigned short)(r >> 16);
}

// ---------------------------------------------------------------------------
// Prep:
//  job 1: w2mf = w2 (72x256) bf16, MFMA A-frag order (tm=0..4, s=0..7)
//  job 2: w_outmf = w_out (64x64) bf16, MFMA A-frag order (tm=0..3, s=0..1)
//  job 3: w1p[o*8+kk] = w1[o*9+k(kk)], k skips center.
// ---------------------------------------------------------------------------
__global__ __launch_bounds__(256) void k_prep(const float* __restrict__ w2,
                                              const float* __restrict__ w_out,
                                              const float* __restrict__ w1,
                                              unsigned short* __restrict__ w2mf,
                                              unsigned short* __restrict__ w_outmf,
                                              float* __restrict__ w1p) {
    int idx = blockIdx.x * 256 + threadIdx.x;
    if (idx < 20480) {
        int j  = idx & 7;
        int l  = (idx >> 3) & 63;
        int ts = idx >> 9;             // tm*8+s, 0..39
        int tm = ts >> 3, s = ts & 7;
        int jrow = tm * 16 + (l & 15);
        int k    = s * 32 + (l >> 4) * 8 + j;
        float v = (jrow < JCN) ? w2[jrow * OCN + k] : 0.f;
        w2mf[idx] = f2bf(v);
    } else if (idx < 24576) {
        int r  = idx - 20480;          // 0..4095
        int j  = r & 7;
        int l  = (r >> 3) & 63;
        int ts = r >> 9;               // tm*2+s, 0..7
        int tm = ts >> 1, s = ts & 1;
        int m  = tm * 16 + (l & 15);
        int k  = s * 32 + (l >> 4) * 8 + j;
        w_outmf[r] = f2bf(w_out[m * CN + k]);
    } else if (idx < 26624) {
        int r = idx - 24576;           // 0..2047
        int o = r >> 3, kk = r & 7;
        int k = kk < 4 ? kk : kk + 1;
        w1p[r] = w1[o * 9 + k];
    }
}

// ---------------------------------------------------------------------------
// K1: offsets t + fused x1 copy.  PARKED at the r5 split-K form (~50 us).
// Five structures tried (direct r2=51, LDS-stage r3=77, lean-instr r4=70,
// split-K r5=51, shuffle-stencil r7=52, dist-2 prefetch r8=67): 50 us is a
// latency/request floor invisible to further source restructuring.
// XCD band swizzle kept (FETCH 46.9 -> 12.3 MB).
// ---------------------------------------------------------------------------
__global__ __launch_bounds__(512, 4) void k_offsets(const float* __restrict__ x,
                                                    const float* __restrict__ w1p,
                                                    const unsigned short* __restrict__ w2mf,
                                                    const float* __restrict__ b2,
                                                    float* __restrict__ t_out,
                                                    float* __restrict__ x_copy) {
    __shared__ float red[4 * 64 * 21];   // 21504 B; [wv][lane][20 padded to 21]

    // swizzle: orig flat id f, XCD = f%8 (round-robin); give XCD k slots
    // [144k, 144k+144) -> contiguous y-band of 48 rows per XCD.
    const int f  = blockIdx.x + 3 * blockIdx.y + 576 * blockIdx.z;
    const int nn = (f & 7) * 144 + (f >> 3);
    const int bx = nn % 3;
    const int by = (nn / 3) % 192;
    const int bz = nn / 576;

    const int tid  = threadIdx.x;
    const int wave = tid >> 6;
    const int sgrp = wave >> 2;          // K-half: 0 -> s=0..3, 1 -> s=4..7
    const int wv   = wave & 3;           // 16-pixel strip
    const int lane = tid & 63;
    const int q    = lane >> 4;
    const int n    = lane & 15;
    const int x0   = bx * 64;
    const int y    = by;
    const int b    = bz;
    const int xcol = x0 + wv * 16 + n;
    const float* xb = x + (size_t)b * CN * HWN;

    auto load_chunk = [&](int s, float (*ld)[9]) {
        #pragma unroll
        for (int cc = 0; cc < 2; ++cc) {
            int c = 8 * s + 2 * q + cc;
            const float* xp = xb + (size_t)c * HWN;
            #pragma unroll
            for (int k = 0; k < 9; ++k) {
                int ky = k / 3, kx = k - 3 * ky;
                int yy = y - 1 + ky, xx = xcol - 1 + kx;
                float v = 0.f;
                if ((unsigned)yy < (unsigned)HN && (unsigned)xx < (unsigned)WN)
                    v = xp[yy * WN + xx];
                ld[cc][k] = v;
            }
        }
    };

    f32x4 acc[5];
    #pragma unroll
    for (int t = 0; t < 5; ++t) acc[t] = (f32x4){0.f, 0.f, 0.f, 0.f};

    const bf16x8* ap = (const bf16x8*)w2mf + lane;

    // run this wave-group's K-half with compile-time s (unrolled sgi branch
    // keeps the exact round-2 load scheduling)
    #pragma unroll
    for (int sgi = 0; sgi < 2; ++sgi) {
        if (sgrp == sgi) {
            float lbuf[2][2][9];
            load_chunk(sgi * 4, lbuf[0]);
            #pragma unroll
            for (int ss = 0; ss < 4; ++ss) {
                const int s = sgi * 4 + ss;
                if (ss < 3) load_chunk(s + 1, lbuf[(ss + 1) & 1]);
                float (*ld)[9] = lbuf[ss & 1];

                float dd[2][8];
                #pragma unroll
                for (int cc = 0; cc < 2; ++cc) {
                    int c = 8 * s + 2 * q + cc;
                    float ctr = ld[cc][4];
                    x_copy[((size_t)b * CN + c) * HWN + y * WN + xcol] = ctr;
                    #pragma unroll
                    for (int kk = 0; kk < 8; ++kk) {
                        int k = kk < 4 ? kk : kk + 1;
                        dd[cc][kk] = ld[cc][k] - ctr;
                    }
                }

                bf16x8 bfr;
                const float4* wp = (const float4*)(w1p + (size_t)(s * 32 + q * 8) * 8);
                #pragma unroll
                for (int j = 0; j < 8; ++j) {
                    float4 wa = wp[2 * j];
                    float4 wb = wp[2 * j + 1];
                    const float* d = dd[j >> 2];
                    float a = wa.x * d[0] + wa.y * d[1] + wa.z * d[2] + wa.w * d[3]
                            + wb.x * d[4] + wb.y * d[5] + wb.z * d[6] + wb.w * d[7];
                    bfr[j] = (short)f2bf(a);
                }

                #pragma unroll
                for (int tm = 0; tm < 5; ++tm) {
                    bf16x8 af = ap[(tm * 8 + s) * 64];
                    acc[tm] = __builtin_amdgcn_mfma_f32_16x16x32_bf16(af, bfr, acc[tm], 0, 0, 0);
                }
            }
        }
    }

    // combine the two K-halves via LDS (stride 21: conflict-free)
    float* rp = &red[(wv * 64 + lane) * 21];
    if (sgrp == 1) {
        #pragma unroll
        for (int tm = 0; tm < 5; ++tm)
            #pragma unroll
            for (int r = 0; r < 4; ++r)
                rp[tm * 4 + r] = acc[tm][r];
    }
    __syncthreads();
    if (sgrp == 0) {
        // Epilogue (D layout: col=lane&15, row=q*4+reg)
        float* tb = t_out + (size_t)b * JCN * HWN + y * WN + x0 + wv * 16 + n;
        #pragma unroll
        for (int tm = 0; tm < 5; ++tm) {
            #pragma unroll
            for (int r = 0; r < 4; ++r) {
                int j = tm * 16 + q * 4 + r;
                if (j < JCN)
                    tb[(size_t)j * HWN] = acc[tm][r] + rp[tm * 4 + r] + b2[j];
            }
        }
    }
}

// ---------------------------------------------------------------------------
// K2: depthwise deformable conv.  Channel-interleaved LDS window (r6 win:
// 2 x ds_read_b128 per 8-ch corner).  Round 9: halo 4 -> 2 — offsets are
// ~N(0,0.2^2) so |off|>1 is a >4-sigma event handled by the (correct)
// global-path else branch; LDS 35.1 -> 23.1 KB lifts residency 4 -> 7
// blocks/CU to cover the latency that 44% VALUBusy / 32% occupancy exposed.
// y written bf16 in MFMA B-frag order (one 16B store/thread).  XCD swizzle
// pairs both chunks of a deform group on the same XCD.
// ---------------------------------------------------------------------------
__device__ __forceinline__ float dsample(const float* __restrict__ p, int yi, int xi) {
    if ((unsigned)yi < (unsigned)HN && (unsigned)xi < (unsigned)WN)
        return p[yi * WN + xi];
    return 0.f;
}

__global__ __launch_bounds__(256, 4) void k_deform(const float* __restrict__ x,
                                                   const float* __restrict__ t_in,
                                                   const float* __restrict__ wdef,
                                                   unsigned short* __restrict__ y_out) {
    __shared__ float xs[XH * XW * CI];                // 23088 B
    __shared__ float wks[9 * 8];                      // [k][cc]
    __shared__ float wsums[8];

    // swizzle: 2304 blocks = 8 XCD * 288 slots; slot = (tile<<1)|cm;
    // XCD k runs zz = {2k, 2k+1} = both chunks of deform-group g=k%4, b=k/4.
    const int f    = blockIdx.x + 6 * blockIdx.y + 144 * blockIdx.z;  // 0..2303
    const int slot = f >> 3;
    const int xcd  = f & 7;
    const int tile = slot >> 1;
    const int cm   = slot & 1;
    const int zz   = 2 * xcd + cm;            // 0..15
    const int bx   = tile % 6;
    const int byy  = tile / 6;

    const int x0   = bx * SN;
    const int yr0  = byy * DROWS;
    const int b    = zz >> 3;
    const int chunk = zz & 7;                 // 8-channel chunk
    const int g    = chunk >> 1;              // deform group
    const int tid  = threadIdx.x;
    const int r    = tid >> 5;                // output row within tile
    const int px   = tid & 31;
    const int row_lo = yr0 - XRT;
    const int col_lo = x0 - XCL;
    const float* xb = x + (size_t)b * CN * HWN;

    // prefetch this thread's 18 offsets into registers (coalesced)
    float dyr[9], dxr[9];
    {
        const float* tbp = t_in + ((size_t)b * JCN + g * 18) * HWN
                         + (yr0 + r) * WN + x0 + px;
        #pragma unroll
        for (int k = 0; k < 9; ++k) {
            dyr[k] = tbp[(size_t)(2 * k) * HWN];
            dxr[k] = tbp[(size_t)(2 * k + 1) * HWN];
        }
    }

    // stage x window (zero-filled outside image), channel-interleaved
    for (int idx = tid; idx < 8 * XH * XW; idx += 256) {
        int cc  = idx / (XH * XW);
        int rem = idx - cc * (XH * XW);
        int rr  = rem / XW;
        int col = rem - rr * XW;
        int yy  = row_lo + rr;
        int xx  = col_lo + col;
        float v = 0.f;
        if ((unsigned)yy < (unsigned)HN && (unsigned)xx < (unsigned)WN)
            v = xb[(size_t)(chunk * 8 + cc) * HWN + yy * WN + xx];
        xs[(rr * XW + col) * CI + cc] = v;
    }
    // stage weights
    if (tid < 72) {
        int k = tid >> 3, cc = tid & 7;
        wks[tid] = wdef[(chunk * 8 + cc) * 9 + k];
    } else if (tid < 80) {
        int cc = tid - 72;
        float s = 0.f;
        #pragma unroll
        for (int k = 0; k < 9; ++k) s += wdef[(chunk * 8 + cc) * 9 + k];
        wsums[cc] = s;
    }
    __syncthreads();

    float acc[8];
    {
        const float* ctr = xs + ((XRT + r) * XW + XCL + px) * CI;
        f32x4 c0 = *(const f32x4*)ctr;
        f32x4 c1 = *(const f32x4*)(ctr + 4);
        f32x4 w0 = *(const f32x4*)&wsums[0];
        f32x4 w1 = *(const f32x4*)&wsums[4];
        #pragma unroll
        for (int i = 0; i < 4; ++i) {
            acc[i]     = -c0[i] * w0[i];
            acc[4 + i] = -c1[i] * w1[i];
        }
    }

    const float ry_basef = (float)(yr0 + r - 1);
    const float rx_basef = (float)(x0 + px - 1);

    #pragma unroll
    for (int k = 0; k < 9; ++k) {
        const int ky = k / 3, kx = k - 3 * ky;
        float py  = ry_basef + (float)ky + dyr[k];
        float pxf = rx_basef + (float)kx + dxr[k];
        float y0f = floorf(py), x0f = floorf(pxf);
        float wy = py - y0f, wx = pxf - x0f;
        int yi = (int)y0f, xi = (int)x0f;
        int ry = yi - row_lo, rx = xi - col_lo;
        float omwy = 1.f - wy, omwx = 1.f - wx;
        float w00 = omwy * omwx;
        float w01 = omwy * wx;
        float w10 = wy * omwx;
        float w11 = wy * wx;
        float4 wka = *(const float4*)&wks[k * 8];
        float4 wkb = *(const float4*)&wks[k * 8 + 4];
        if ((unsigned)ry < (XH - 1) && (unsigned)rx < (XW - 1)) {
            const float* p00 = xs + (ry * XW + rx) * CI;
            const float* p10 = p00 + XW * CI;
            f32x4 a0 = *(const f32x4*)p00;            // (ry, rx)   ch0-3
            f32x4 a1 = *(const f32x4*)(p00 + 4);      //            ch4-7
            f32x4 b0 = *(const f32x4*)(p00 + CI);     // (ry, rx+1) ch0-3
            f32x4 b1 = *(const f32x4*)(p00 + CI + 4);
            f32x4 c0 = *(const f32x4*)p10;            // (ry+1, rx) ch0-3
            f32x4 c1 = *(const f32x4*)(p10 + 4);
            f32x4 d0 = *(const f32x4*)(p10 + CI);     // (ry+1,rx+1)ch0-3
            f32x4 d1 = *(const f32x4*)(p10 + CI + 4);
            #pragma unroll
            for (int i = 0; i < 4; ++i) {
                float bil0 = a0[i] * w00 + b0[i] * w01 + c0[i] * w10 + d0[i] * w11;
                float bil1 = a1[i] * w00 + b1[i] * w01 + c1[i] * w10 + d1[i] * w11;
                acc[i]     += (&wka.x)[i] * bil0;
                acc[4 + i] += (&wkb.x)[i] * bil1;
            }
        } else {
            float wkv[8] = {wka.x, wka.y, wka.z, wka.w, wkb.x, wkb.y, wkb.z, wkb.w};
            #pragma unroll
            for (int c = 0; c < 8; ++c) {
                const float* xp = xb + (size_t)(chunk * 8 + c) * HWN;
                float v00 = dsample(xp, yi,     xi);
                float v01 = dsample(xp, yi,     xi + 1);
                float v10 = dsample(xp, yi + 1, xi);
                float v11 = dsample(xp, yi + 1, xi + 1);
                float bil = v00 * w00 + v01 * w01 + v10 * w10 + v11 * w11;
                acc[c] += wkv[c] * bil;
            }
        }
    }

    // bf16 B-frag store: y_bf[b][P][s][q][n][j], j contiguous (16B / thread)
    u16x8 pk;
    #pragma unroll
    for (int c = 0; c < 8; ++c) pk[c] = f2bf(acc[c]);
    const int P = (yr0 + r) * (WN / 16) + ((x0 + px) >> 4);
    unsigned short* yo = y_out
        + ((((size_t)b * PGRPS + P) * 2 + (chunk >> 2)) * 4 + (chunk & 3)) * 128
        + (px & 15) * 8;
    *(u16x8*)yo = pk;
}

// ---------------------------------------------------------------------------
// K3: m = w_out . y via MFMA.  y arrives bf16 in B-frag order: two 16B loads
// per thread replace 64 scalar plane-strided loads + 64 f2bf.  (r7's LDS
// transpose epilogue regressed the total — direct stores kept.)
// ---------------------------------------------------------------------------
__global__ __launch_bounds__(256, 8) void k_final(const unsigned short* __restrict__ y_bf,
                                                  const unsigned short* __restrict__ womf,
                                                  float* __restrict__ m_out) {
    const int tid  = threadIdx.x;
    const int wv   = tid >> 6;
    const int lane = tid & 63;
    const int q    = lane >> 4;
    const int n    = lane & 15;
    const int yr   = blockIdx.y;
    const int b    = blockIdx.z;
    const int P    = yr * (WN / 16) + blockIdx.x * 4 + wv;

    const unsigned short* yp = y_bf + ((size_t)b * PGRPS + P) * 1024;
    bf16x8 bfr0 = *(const bf16x8*)(yp + (0 * 64 + q * 16 + n) * 8);
    bf16x8 bfr1 = *(const bf16x8*)(yp + (1 * 64 + q * 16 + n) * 8);

    const bf16x8* ap = (const bf16x8*)womf + lane;
    f32x4 acc[4];
    #pragma unroll
    for (int tm = 0; tm < 4; ++tm) acc[tm] = (f32x4){0.f, 0.f, 0.f, 0.f};
    #pragma unroll
    for (int tm = 0; tm < 4; ++tm) {
        acc[tm] = __builtin_amdgcn_mfma_f32_16x16x32_bf16(ap[(tm * 2 + 0) * 64], bfr0, acc[tm], 0, 0, 0);
        acc[tm] = __builtin_amdgcn_mfma_f32_16x16x32_bf16(ap[(tm * 2 + 1) * 64], bfr1, acc[tm], 0, 0, 0);
    }

    // D layout: col=lane&15, row=q*4+reg ; o = tm*16 + q*4 + r
    float* mb = m_out + (size_t)b * CN * HWN + yr * WN + blockIdx.x * 64 + wv * 16 + n;
    #pragma unroll
    for (int tm = 0; tm < 4; ++tm) {
        #pragma unroll
        for (int r = 0; r < 4; ++r)
            mb[(size_t)(tm * 16 + q * 4 + r) * HWN] = acc[tm][r];
    }
}

// ---------------------------------------------------------------------------
extern "C" void kernel_launch(void* const* d_in, const int* in_sizes, int n_in,
                              void* d_out, int out_size, void* d_ws, size_t ws_size,
                              hipStream_t stream) {
    const float* x1    = (const float*)d_in[0];   // 2*64*192*192
    const float* w_off1 = (const float*)d_in[1];  // 256*9
    const float* w_off2 = (const float*)d_in[2];  // 72*256
    const float* b_off2 = (const float*)d_in[3];  // 72
    const float* w_def = (const float*)d_in[4];   // 64*9
    const float* w_out = (const float*)d_in[5];   // 64*64

    float* out = (float*)d_out;
    const size_t n_x = (size_t)BN * CN * HWN;     // 4718592
    float* out_x1 = out;                          // output 0: x1 copy (fused into k_offsets)
    float* out_m  = out + n_x;                    // output 1: m

    // Workspace layout (bytes)
    char* ws0 = (char*)d_ws;
    unsigned short* w2mf   = (unsigned short*)ws0;            // 20480 bf16 = 40960 B
    unsigned short* w_outmf = (unsigned short*)(ws0 + 40960); // 4096 bf16 = 8192 B
    float* w1p    = (float*)(ws0 + 49152);                    // 2048 f = 8192 B
    float* t_ws   = (float*)(ws0 + 57344);                    // 2*72*36864 f = 21233664 B
    unsigned short* y_bf = (unsigned short*)(ws0 + 57344 + 21233664); // 2*2304*1024 u16 = 9.44 MB

    k_prep<<<dim3(104), dim3(256), 0, stream>>>(w_off2, w_out, w_off1, w2mf, w_outmf, w1p);
    k_offsets<<<dim3(WN / 64, HN, BN), dim3(512), 0, stream>>>(x1, w1p, w2mf, b_off2,
                                                               t_ws, out_x1);
    k_deform<<<dim3(WN / SN, HN / DROWS, BN * 8), dim3(256), 0, stream>>>(x1, t_ws, w_def, y_bf);
    k_final<<<dim3(WN / 64, HN, BN), dim3(256), 0, stream>>>(y_bf, w_outmf, out_m);
}